// Round 17
// baseline (563.718 us; speedup 1.0000x reference)
//
#include <hip/hip_runtime.h>
#include <hip/hip_bf16.h>
#include <stdint.h>

// Problem constants (CausalSelfAttention_22703197127379)
#define T_DIM 8192
#define E_DIM 4096
#define NQH   32
#define HD    128
#define QSZ   (NQH * HD)          // 4096
#define QKV_COLS 6144             // Q_SIZE + 2*KV_SIZE (w_qkv leading dim)

typedef unsigned short u16;
typedef __attribute__((ext_vector_type(8))) short   bf16x8;
typedef __attribute__((ext_vector_type(4))) float   f32x4;
typedef __attribute__((ext_vector_type(4))) unsigned short u16x4;

__device__ __forceinline__ u16 f2bf(float f) {
    uint32_t u = __float_as_uint(f);
    u += 0x7fffu + ((u >> 16) & 1u);   // round-to-nearest-even
    return (u16)(u >> 16);
}
__device__ __forceinline__ float bf2f(u16 u) {
    return __uint_as_float(((uint32_t)u) << 16);
}

// async global->LDS, 16 bytes per lane (dest = wave-uniform base + lane*16)
__device__ __forceinline__ void gload_lds16(u16* lds, const u16* g) {
    __builtin_amdgcn_global_load_lds(
        (const __attribute__((address_space(1))) uint32_t*)g,
        (__attribute__((address_space(3))) uint32_t*)lds,
        16, 0, 0);
}

// ---------------- fp32 [K][ldW] (col slice) -> bf16 transposed [N][K] ----------------
// (standalone: fallback path only)
__global__ void transpose_conv(const float* __restrict__ W, u16* __restrict__ Wt,
                               int K, int N, int ldW, int colOff) {
    __shared__ float tile[32][33];
    const int tx = threadIdx.x, ty = threadIdx.y;
    const int n0 = blockIdx.x * 32, k0 = blockIdx.y * 32;
#pragma unroll
    for (int j = 0; j < 4; ++j) {
        int k = k0 + ty + j * 8;
        tile[ty + j * 8][tx] = W[(size_t)k * ldW + colOff + n0 + tx];
    }
    __syncthreads();
#pragma unroll
    for (int j = 0; j < 4; ++j) {
        int n = n0 + ty + j * 8;
        Wt[(size_t)n * K + k0 + tx] = f2bf(tile[tx][ty + j * 8]);
    }
}

// ====== fused pre-pass: H convert + Wq transpose [+ Wo transpose] + RoPE table ======
// Independent memory-bound jobs in ONE dispatch (blockIdx-range sections).
// libm (powf/sincosf) is safe here — no MFMA accumulator live (rounds 6/7
// lesson: NEVER call libm inside the GEMM epilogue).
#define CONV_BLOCKS 2048
#define TWQ_BLOCKS  ((QSZ / 32) * (E_DIM / 32))   // 16384
#define TWO_BLOCKS  ((E_DIM / 32) * (QSZ / 32))   // 16384
#define TAB_BLOCKS  ((T_DIM * 64) / 256)          // 2048

template <bool FUSE_WO>
__global__ void prepass(const float* __restrict__ hidden, u16* __restrict__ Hb,
                        const float* __restrict__ w_qkv, u16* __restrict__ WqT,
                        const float* __restrict__ w_o,  u16* __restrict__ WoT,
                        const int* __restrict__ pos, float2* __restrict__ tab) {
    __shared__ float tile[32][33];
    const int b = blockIdx.x;
    const int tid = threadIdx.x;
    if (b < CONV_BLOCKS) {
        // --- section 0: hidden fp32 -> bf16, float4-vectorized grid-stride ---
        const size_t n4 = (size_t)T_DIM * E_DIM / 4;   // 8,388,608
        size_t i = (size_t)b * 256 + tid;
        const size_t stride = (size_t)CONV_BLOCKS * 256;
        for (; i < n4; i += stride) {
            float4 v = ((const float4*)hidden)[i];
            u16x4 o;
            o.x = f2bf(v.x); o.y = f2bf(v.y); o.z = f2bf(v.z); o.w = f2bf(v.w);
            ((u16x4*)Hb)[i] = o;
        }
    } else if (b < CONV_BLOCKS + TWQ_BLOCKS) {
        // --- section 1: WqT[n][k] = w_qkv[k][n], n<4096, ldW=6144 ---
        const int t  = b - CONV_BLOCKS;
        const int tx = tid & 31, ty = tid >> 5;
        const int n0 = (t & 127) * 32;      // QSZ/32 = 128 n-tiles
        const int k0 = (t >> 7) * 32;       // E/32   = 128 k-tiles
#pragma unroll
        for (int j = 0; j < 4; ++j) {
            int k = k0 + ty + j * 8;
            tile[ty + j * 8][tx] = w_qkv[(size_t)k * QKV_COLS + n0 + tx];
        }
        __syncthreads();
#pragma unroll
        for (int j = 0; j < 4; ++j) {
            int n = n0 + ty + j * 8;
            WqT[(size_t)n * E_DIM + k0 + tx] = f2bf(tile[tx][ty + j * 8]);
        }
    } else if (FUSE_WO && b < CONV_BLOCKS + TWQ_BLOCKS + TWO_BLOCKS) {
        // --- section 2: WoT[n][k] = w_o[k][n], K=QSZ rows, N=E cols, ldW=E ---
        const int t  = b - CONV_BLOCKS - TWQ_BLOCKS;
        const int tx = tid & 31, ty = tid >> 5;
        const int n0 = (t & 127) * 32;      // E/32   = 128 n-tiles
        const int k0 = (t >> 7) * 32;       // QSZ/32 = 128 k-tiles
#pragma unroll
        for (int j = 0; j < 4; ++j) {
            int k = k0 + ty + j * 8;
            tile[ty + j * 8][tx] = w_o[(size_t)k * E_DIM + n0 + tx];
        }
        __syncthreads();
#pragma unroll
        for (int j = 0; j < 4; ++j) {
            int n = n0 + ty + j * 8;
            WoT[(size_t)n * QSZ + k0 + tx] = f2bf(tile[tx][ty + j * 8]);
        }
    } else {
        // --- last section: tab[t][d] = (cos, sin)(pos[t] * theta^(-d/64)) ---
        const int idx = (b - CONV_BLOCKS - TWQ_BLOCKS - (FUSE_WO ? TWO_BLOCKS : 0)) * 256 + tid;
        const int t = idx >> 6, d = idx & 63;
        float inv = powf(10000.0f, -(float)d * (1.0f / 64.0f));
        float fr  = (float)pos[t] * inv;
        float s, c;
        sincosf(fr, &s, &c);
        tab[idx] = make_float2(c, s);
    }
}

// ======================= read-ahead 8-phase bf16 GEMM (r14 core) =======================
// r8 core: stage map, counted vmcnt(4), one-ahead reads. r13: 2D-chunked XCD
// map (FETCH 551->202MB). r14: pre-barrier reads at non-pub phases.
// Failed restructures: r6 (spill), r9 (-28%), r10 (-15%), r15 (RACE — see
// race rule below).
// r17 delta (2 lines): REMOVE s_setprio around MFMA clusters. Cycle audit:
// observed phase = 1036cy ~ DS-pipe(565) + MFMA(516) SERIAL, though the dep
// graph permits overlap. Theory: in barrier-lockstep, setprio(1) during the
// MFMA window starves other waves' ds_read issue (priority inversion) ->
// pipes serialize. T5 catalog: setprio pays only with wave role diversity
// (m218b); lockstep GEMM was null/negative (m190).
// r15's race rule (do not violate): with 2-buffer LDS + counted vmcnt, an LDS
// region may be overwritten only AFTER the barrier that FOLLOWS the phase of
// its last readers' first-consuming MFMA.
__device__ __forceinline__ void store_out(u16* p, float v)  { *p = f2bf(v); }
__device__ __forceinline__ void store_out(float* p, float v){ *p = v; }

#define BARS()    do { __builtin_amdgcn_sched_barrier(0); __builtin_amdgcn_s_barrier(); } while (0)
#define BARSPUB() do { __builtin_amdgcn_sched_barrier(0); __builtin_amdgcn_s_barrier(); \
                       __builtin_amdgcn_sched_barrier(0); } while (0)
#define VMC(N) asm volatile("s_waitcnt vmcnt(%0)" :: "n"(N) : "memory")

// stage one half-tile (128 rows x 64 K, one operand): 2 gloads/thread
#define STG_A(buf, h, kOff) do { \
    const u16* s_ = sA + (size_t)(h) * 128 * K + (kOff); \
    u16* d_ = dL + (buf) * 32768 + (h) * 8192; \
    gload_lds16(d_, s_); gload_lds16(d_ + 4096, s_ + (size_t)64 * K); } while (0)
#define STG_B(buf, h, kOff) do { \
    const u16* s_ = sB + (size_t)(h) * 128 * K + (kOff); \
    u16* d_ = dL + 16384 + (buf) * 32768 + (h) * 8192; \
    gload_lds16(d_, s_); gload_lds16(d_ + 4096, s_ + (size_t)64 * K); } while (0)

// read A frags mi in [miBase, miBase+4), both K-slices
#define RD_A(buf, miBase, d0, d1) do { _Pragma("unroll") \
    for (int m = 0; m < 4; ++m) { \
        const u16* p_ = lds + (buf) * 32768 + wm * 8192 + ((miBase) + m) * 1024 + aRow; \
        d0[m] = *(const bf16x8*)(p_ + cOf0); \
        d1[m] = *(const bf16x8*)(p_ + cOf1); } } while (0)
// read B frags ni in [niBase, niBase+2), both K-slices.
// B-row = ni*64 + wn*16 + lr -> half = ni>>1, row_in_half = (ni&1)*64+wn*16+lr
#define RD_B(buf, niBase, d0, d1) do { _Pragma("unroll") \
    for (int n = 0; n < 2; ++n) { \
        const int ni_ = (niBase) + n; \
        const u16* p_ = lds + (buf) * 32768 + 16384 + (ni_ >> 1) * 8192 + \
                        ((ni_ & 1) * 64 + wn * 16) * 64 + aRow; \
        d0[n] = *(const bf16x8*)(p_ + cOf0); \
        d1[n] = *(const bf16x8*)(p_ + cOf1); } } while (0)

// r17: no setprio (priority inversion in lockstep schedule — see header)
#define MM(miBase, niBase, A0, A1, B0, B1) do { \
    _Pragma("unroll") for (int m = 0; m < 4; ++m) \
    _Pragma("unroll") for (int n = 0; n < 2; ++n) { \
        acc[(miBase) + m][(niBase) + n] = __builtin_amdgcn_mfma_f32_16x16x32_bf16( \
            A0[m], B0[n], acc[(miBase) + m][(niBase) + n], 0, 0, 0); \
        acc[(miBase) + m][(niBase) + n] = __builtin_amdgcn_mfma_f32_16x16x32_bf16( \
            A1[m], B1[n], acc[(miBase) + m][(niBase) + n], 0, 0, 0); } \
    } while (0)

template <typename OutT, bool ROPE>
__global__ __launch_bounds__(512, 2) void gemm256(const u16* __restrict__ A,
                                                  const u16* __restrict__ Bt,
                                                  OutT* __restrict__ C,
                                                  const float2* __restrict__ tab,
                                                  int M, int N, int K) {
    __shared__ u16 lds[65536];   // 2 bufs x (A 256x64 + B 256x64) bf16 = 128 KiB
    const int tid  = threadIdx.x;
    const int lane = tid & 63;
    const int wid  = tid >> 6;
    const int wm = wid >> 2;           // 0..1 -> 128 rows each
    const int wn = wid & 3;            // 0..3 -> 16-col granules (col=ni*64+wn*16+lr)
    const int lr  = lane & 15;
    const int kq  = lane >> 4;         // 0..3
    const int lr7 = lr & 7;
    const int aRow = lr * 64;                       // row offset within half (elems)
    const int cOf0 = ((kq) ^ lr7) << 3;             // K-slice 0 chunk (swizzled)
    const int cOf1 = ((4 + kq) ^ lr7) << 3;         // K-slice 1 chunk

    // ---- 2D-chunked XCD tile mapping (bijective; FETCH 551->202MB) ----
    const int nwg = gridDim.x;
    const int bid = blockIdx.x;
    const int numM = M >> 8;
    int tileR, tileC;
    if (numM == 32 && nwg == 512) {
        const int x = bid & 7, i = bid >> 3;
        tileR = ((x >> 1) << 3) + (i & 7);
        tileC = ((x & 1) << 3) + (i >> 3);
    } else {
        const int cpx = nwg >> 3;
        const int swz = (bid & 7) * cpx + (bid >> 3);
        tileR = swz % numM;
        tileC = swz / numM;
    }
    const size_t rowBase = (size_t)tileR << 8;
    const size_t colBase = (size_t)tileC << 8;

    // staging addresses: half-tile = 1024 chunks of 16B; thread owns chunks
    // tid (row r0=tid>>3) and tid+512 (row r0+64); src col pre-swizzled.
    const int r0 = tid >> 3;
    const int cS = (((tid & 7) ^ (r0 & 7)) << 3);
    const u16* sA = A  + (rowBase + r0) * (size_t)K + cS;
    const u16* sB = Bt + (colBase + r0) * (size_t)K + cS;
    u16* dL = &lds[0] + tid * 8;       // linear chunk dest (+4096 elems for chunk tid+512)

    f32x4 acc[8][4];
#pragma unroll
    for (int i = 0; i < 8; ++i)
#pragma unroll
        for (int j = 0; j < 4; ++j)
            acc[i][j] = (f32x4){0.f, 0.f, 0.f, 0.f};

    bf16x8 a0K0[4], a0K1[4], a4K0[4], a4K1[4];
    bf16x8 b01eK0[2], b01eK1[2], b01oK0[2], b01oK1[2], b23K0[2], b23K1[2];

    // prologue: buf0 <- tile0, buf1.B <- tile1; drain buf0 (leave buf1.B in
    // flight), publish, then pre-read P0's operands (a03+b01_e of tile0).
    STG_A(0, 0, 0); STG_A(0, 1, 0); STG_B(0, 0, 0); STG_B(0, 1, 0);
    STG_B(1, 0, 64); STG_B(1, 1, 64);
    VMC(4);
    BARSPUB();
    RD_A(0, 0, a0K0, a0K1);
    RD_B(0, 0, b01eK0, b01eK1);

    const int nIter = K >> 7;          // K/128, K % 128 == 0
    for (int it = 0; it < nIter; ++it) {
        const int k1  = ((it << 1) + 1) << 6;                    // tile 2i+1 (always valid)
        const int kt2 = ((it << 1) + 2) << 6;
        const int kt3 = ((it << 1) + 3) << 6;
        const int k2c = (kt2 <= K - 64) ? kt2 : 0;               // clamp OOB tail stages
        const int k3c = (kt3 <= K - 64) ? kt3 : 0;               // (data never consumed)

        // P0: read b23(buf0) PRE-bar (published @P7-prev) ; MFMA Q00
        STG_A(1, 0, k1);
        RD_B(0, 2, b23K0, b23K1);
        BARS();
        MM(0, 0, a0K0, a0K1, b01eK0, b01eK1);
        // P1: read a47(buf0) PRE-bar (published @P7-prev) ; MFMA Q02
        STG_A(1, 1, k1);
        RD_A(0, 4, a4K0, a4K1);
        BARS();
        MM(0, 2, a0K0, a0K1, b23K0, b23K1);
        // P2: MFMA Q42 ; no reads
        STG_B(0, 0, k2c);
        BARS();
        MM(4, 2, a4K0, a4K1, b23K0, b23K1);
        // P3: drain buf1, publish ; reads MUST stay post-bar ; MFMA Q40
        STG_B(0, 1, k2c);
        VMC(4);
        BARSPUB();
        RD_A(1, 0, a0K0, a0K1);
        RD_B(1, 0, b01oK0, b01oK1);
        MM(4, 0, a4K0, a4K1, b01eK0, b01eK1);
        // P4: read b23(buf1) PRE-bar (published @P3) ; MFMA Q00'
        STG_A(0, 0, k2c);
        RD_B(1, 2, b23K0, b23K1);
        BARS();
        MM(0, 0, a0K0, a0K1, b01oK0, b01oK1);
        // P5: read a47(buf1) PRE-bar (published @P3) ; MFMA Q02'
        STG_A(0, 1, k2c);
        RD_A(1, 4, a4K0, a4K1);
        BARS();
        MM(0, 2, a0K0, a0K1, b23K0, b23K1);
        // P6: MFMA Q42' ; no reads
        STG_B(1, 0, k3c);
        BARS();
        MM(4, 2, a4K0, a4K1, b23K0, b23K1);
        // P7: drain buf0, publish ; reads post-bar ; MFMA Q40'
        STG_B(1, 1, k3c);
        VMC(4);
        BARSPUB();
        RD_A(0, 0, a0K0, a0K1);
        RD_B(0, 0, b01eK0, b01eK1);
        MM(4, 0, a4K0, a4K1, b01oK0, b01oK1);
    }

    asm volatile("s_waitcnt vmcnt(0)" ::: "memory");   // drain leftover stages

    // epilogue: C/D frag layout col = lane&15, row = 4*(lane>>4) + r.
    // Global col = colBase + ni*64 + wn*16 + lr.
    if constexpr (ROPE) {
        const int dIdx = wn * 16 + lr;                   // uniform per lane
#pragma unroll
        for (int mi = 0; mi < 8; ++mi)
#pragma unroll
            for (int r = 0; r < 4; ++r) {
                size_t row = rowBase + wm * 128 + mi * 16 + (kq << 2) + r;
                float2 cs = tab[row * 64 + dIdx];        // (cos, sin) — no libm here
#pragma unroll
                for (int hp = 0; hp < 2; ++hp) {
                    float x1 = acc[mi][hp * 2 + 0][r];
                    float x2 = acc[mi][hp * 2 + 1][r];
                    size_t c1 = colBase + hp * 128 + wn * 16 + lr;
                    C[row * (size_t)N + c1]      = f2bf(x1 * cs.x - x2 * cs.y);
                    C[row * (size_t)N + c1 + 64] = f2bf(x2 * cs.x + x1 * cs.y);
                }
            }
    } else {
#pragma unroll
        for (int mi = 0; mi < 8; ++mi)
#pragma unroll
            for (int ni = 0; ni < 4; ++ni)
#pragma unroll
                for (int r = 0; r < 4; ++r) {
                    size_t row = rowBase + wm * 128 + mi * 16 + (kq << 2) + r;
                    size_t col = colBase + ni * 64 + wn * 16 + lr;
                    store_out(&C[row * (size_t)N + col], acc[mi][ni][r]);
                }
    }
}

extern "C" void kernel_launch(void* const* d_in, const int* in_sizes, int n_in,
                              void* d_out, int out_size, void* d_ws, size_t ws_size,
                              hipStream_t stream) {
    const float* hidden    = (const float*)d_in[0];   // [T][E] fp32
    const int*   positions = (const int*)d_in[1];     // [T] int32
    const float* w_qkv     = (const float*)d_in[2];   // [E][6144] fp32
    const float* w_o       = (const float*)d_in[3];   // [QSZ][E] fp32
    float* out = (float*)d_out;                       // [T][E] fp32

    // workspace layout (bf16): H 64MiB | WqT 32MiB | WoT 32MiB | Q 64MiB = 192MiB.
    // Preferred: tab gets its own 4MiB at 192MiB (ws >= 196MiB) -> Wo-transpose
    // fuses into the prepass. Fallback: tab aliases WoT; Wo-transpose runs
    // between the GEMMs.
    u16* Hb  = (u16*)d_ws;
    u16* WqT = Hb  + (size_t)T_DIM * E_DIM;
    u16* WoT = WqT + (size_t)QSZ * E_DIM;
    u16* Qb  = WoT + (size_t)E_DIM * QSZ;
    const bool fuseWo = ws_size >= ((size_t)196 << 20);
    float2* tab = fuseWo ? (float2*)(Qb + (size_t)T_DIM * QSZ)   // own region @192MiB
                         : (float2*)WoT;                          // alias (fallback)

    if (fuseWo) {
        // 1) ONE fused pre-pass: H convert + Wq-T + Wo-T + RoPE table
        prepass<true><<<CONV_BLOCKS + TWQ_BLOCKS + TWO_BLOCKS + TAB_BLOCKS, 256, 0, stream>>>(
            hidden, Hb, w_qkv, WqT, w_o, WoT, positions, tab);

        // 2) Q = rope(H @ Wq)
        gemm256<u16, true><<<dim3((T_DIM / 256) * (QSZ / 256)), 512, 0, stream>>>(
            Hb, WqT, Qb, tab, T_DIM, QSZ, E_DIM);

        // 3) out = Q @ Wo  (no mid-stream transpose — zero bubble)
        gemm256<float, false><<<dim3((T_DIM / 256) * (E_DIM / 256)), 512, 0, stream>>>(
            Qb, WoT, out, nullptr, T_DIM, E_DIM, QSZ);
    } else {
        // Fallback (r11 measured path)
        prepass<false><<<CONV_BLOCKS + TWQ_BLOCKS + TAB_BLOCKS, 256, 0, stream>>>(
            hidden, Hb, w_qkv, WqT, w_o, WoT, positions, tab);
        gemm256<u16, true><<<dim3((T_DIM / 256) * (QSZ / 256)), 512, 0, stream>>>(
            Hb, WqT, Qb, tab, T_DIM, QSZ, E_DIM);
        dim3 tb(32, 8);
        transpose_conv<<<dim3(E_DIM / 32, QSZ / 32), tb, 0, stream>>>(w_o, WoT, QSZ, E_DIM, E_DIM, 0);
        gemm256<float, false><<<dim3((T_DIM / 256) * (E_DIM / 256)), 512, 0, stream>>>(
            Qb, WoT, out, nullptr, T_DIM, E_DIM, QSZ);
    }
}

// Round 18
// 512.382 us; speedup vs baseline: 1.1002x; 1.1002x over previous
//
#include <hip/hip_runtime.h>
#include <hip/hip_bf16.h>
#include <stdint.h>

// Problem constants (CausalSelfAttention_22703197127379)
#define T_DIM 8192
#define E_DIM 4096
#define NQH   32
#define HD    128
#define QSZ   (NQH * HD)          // 4096
#define QKV_COLS 6144             // Q_SIZE + 2*KV_SIZE (w_qkv leading dim)

typedef unsigned short u16;
typedef __attribute__((ext_vector_type(8))) short   bf16x8;
typedef __attribute__((ext_vector_type(4))) float   f32x4;
typedef __attribute__((ext_vector_type(4))) unsigned short u16x4;

__device__ __forceinline__ u16 f2bf(float f) {
    uint32_t u = __float_as_uint(f);
    u += 0x7fffu + ((u >> 16) & 1u);   // round-to-nearest-even
    return (u16)(u >> 16);
}
__device__ __forceinline__ float bf2f(u16 u) {
    return __uint_as_float(((uint32_t)u) << 16);
}

// async global->LDS, 16 bytes per lane (dest = wave-uniform base + lane*16)
__device__ __forceinline__ void gload_lds16(u16* lds, const u16* g) {
    __builtin_amdgcn_global_load_lds(
        (const __attribute__((address_space(1))) uint32_t*)g,
        (__attribute__((address_space(3))) uint32_t*)lds,
        16, 0, 0);
}

// ---------------- fp32 [K][ldW] (col slice) -> bf16 transposed [N][K] ----------------
// (standalone: fallback path only)
__global__ void transpose_conv(const float* __restrict__ W, u16* __restrict__ Wt,
                               int K, int N, int ldW, int colOff) {
    __shared__ float tile[32][33];
    const int tx = threadIdx.x, ty = threadIdx.y;
    const int n0 = blockIdx.x * 32, k0 = blockIdx.y * 32;
#pragma unroll
    for (int j = 0; j < 4; ++j) {
        int k = k0 + ty + j * 8;
        tile[ty + j * 8][tx] = W[(size_t)k * ldW + colOff + n0 + tx];
    }
    __syncthreads();
#pragma unroll
    for (int j = 0; j < 4; ++j) {
        int n = n0 + ty + j * 8;
        Wt[(size_t)n * K + k0 + tx] = f2bf(tile[tx][ty + j * 8]);
    }
}

// ====== fused pre-pass: H convert + Wq transpose [+ Wo transpose] + RoPE table ======
// Independent memory-bound jobs in ONE dispatch (blockIdx-range sections).
// libm (powf/sincosf) is safe here — no MFMA accumulator live (rounds 6/7
// lesson: NEVER call libm inside the GEMM epilogue).
#define CONV_BLOCKS 2048
#define TWQ_BLOCKS  ((QSZ / 32) * (E_DIM / 32))   // 16384
#define TWO_BLOCKS  ((E_DIM / 32) * (QSZ / 32))   // 16384
#define TAB_BLOCKS  ((T_DIM * 64) / 256)          // 2048

template <bool FUSE_WO>
__global__ void prepass(const float* __restrict__ hidden, u16* __restrict__ Hb,
                        const float* __restrict__ w_qkv, u16* __restrict__ WqT,
                        const float* __restrict__ w_o,  u16* __restrict__ WoT,
                        const int* __restrict__ pos, float2* __restrict__ tab) {
    __shared__ float tile[32][33];
    const int b = blockIdx.x;
    const int tid = threadIdx.x;
    if (b < CONV_BLOCKS) {
        // --- section 0: hidden fp32 -> bf16, float4-vectorized grid-stride ---
        const size_t n4 = (size_t)T_DIM * E_DIM / 4;   // 8,388,608
        size_t i = (size_t)b * 256 + tid;
        const size_t stride = (size_t)CONV_BLOCKS * 256;
        for (; i < n4; i += stride) {
            float4 v = ((const float4*)hidden)[i];
            u16x4 o;
            o.x = f2bf(v.x); o.y = f2bf(v.y); o.z = f2bf(v.z); o.w = f2bf(v.w);
            ((u16x4*)Hb)[i] = o;
        }
    } else if (b < CONV_BLOCKS + TWQ_BLOCKS) {
        // --- section 1: WqT[n][k] = w_qkv[k][n], n<4096, ldW=6144 ---
        const int t  = b - CONV_BLOCKS;
        const int tx = tid & 31, ty = tid >> 5;
        const int n0 = (t & 127) * 32;      // QSZ/32 = 128 n-tiles
        const int k0 = (t >> 7) * 32;       // E/32   = 128 k-tiles
#pragma unroll
        for (int j = 0; j < 4; ++j) {
            int k = k0 + ty + j * 8;
            tile[ty + j * 8][tx] = w_qkv[(size_t)k * QKV_COLS + n0 + tx];
        }
        __syncthreads();
#pragma unroll
        for (int j = 0; j < 4; ++j) {
            int n = n0 + ty + j * 8;
            WqT[(size_t)n * E_DIM + k0 + tx] = f2bf(tile[tx][ty + j * 8]);
        }
    } else if (FUSE_WO && b < CONV_BLOCKS + TWQ_BLOCKS + TWO_BLOCKS) {
        // --- section 2: WoT[n][k] = w_o[k][n], K=QSZ rows, N=E cols, ldW=E ---
        const int t  = b - CONV_BLOCKS - TWQ_BLOCKS;
        const int tx = tid & 31, ty = tid >> 5;
        const int n0 = (t & 127) * 32;      // E/32   = 128 n-tiles
        const int k0 = (t >> 7) * 32;       // QSZ/32 = 128 k-tiles
#pragma unroll
        for (int j = 0; j < 4; ++j) {
            int k = k0 + ty + j * 8;
            tile[ty + j * 8][tx] = w_o[(size_t)k * E_DIM + n0 + tx];
        }
        __syncthreads();
#pragma unroll
        for (int j = 0; j < 4; ++j) {
            int n = n0 + ty + j * 8;
            WoT[(size_t)n * QSZ + k0 + tx] = f2bf(tile[tx][ty + j * 8]);
        }
    } else {
        // --- last section: tab[t][d] = (cos, sin)(pos[t] * theta^(-d/64)) ---
        const int idx = (b - CONV_BLOCKS - TWQ_BLOCKS - (FUSE_WO ? TWO_BLOCKS : 0)) * 256 + tid;
        const int t = idx >> 6, d = idx & 63;
        float inv = powf(10000.0f, -(float)d * (1.0f / 64.0f));
        float fr  = (float)pos[t] * inv;
        float s, c;
        sincosf(fr, &s, &c);
        tab[idx] = make_float2(c, s);
    }
}

// ======================= read-ahead 8-phase bf16 GEMM (r16 FINAL) =======================
// r8 core: stage map, counted vmcnt(4), one-ahead reads. r13: 2D-chunked XCD
// map (FETCH 551->202MB). r14: pre-barrier reads at non-pub phases.
// s_setprio(1) around MFMA clusters: +18% VERIFIED by r16<->r17 A/B
// (221.5 vs 261 us/GEMM; only delta = setprio). Mechanism: barrier skew
// gives wave role diversity (some waves in MFMA cluster, others issuing
// next phase's reads/stages) — T5's paying regime (m218b).
// Failed experiments bracketing this config: r6 (spill), r9 (-28%),
// r10 (-15%), r15 (RACE), r17 (no-setprio, -18%/GEMM).
// r15's race rule (do not violate): with 2-buffer LDS + counted vmcnt, an LDS
// region may be overwritten only AFTER the barrier that FOLLOWS the phase of
// its last readers' first-consuming MFMA.
__device__ __forceinline__ void store_out(u16* p, float v)  { *p = f2bf(v); }
__device__ __forceinline__ void store_out(float* p, float v){ *p = v; }

#define BARS()    do { __builtin_amdgcn_sched_barrier(0); __builtin_amdgcn_s_barrier(); } while (0)
#define BARSPUB() do { __builtin_amdgcn_sched_barrier(0); __builtin_amdgcn_s_barrier(); \
                       __builtin_amdgcn_sched_barrier(0); } while (0)
#define VMC(N) asm volatile("s_waitcnt vmcnt(%0)" :: "n"(N) : "memory")

// stage one half-tile (128 rows x 64 K, one operand): 2 gloads/thread
#define STG_A(buf, h, kOff) do { \
    const u16* s_ = sA + (size_t)(h) * 128 * K + (kOff); \
    u16* d_ = dL + (buf) * 32768 + (h) * 8192; \
    gload_lds16(d_, s_); gload_lds16(d_ + 4096, s_ + (size_t)64 * K); } while (0)
#define STG_B(buf, h, kOff) do { \
    const u16* s_ = sB + (size_t)(h) * 128 * K + (kOff); \
    u16* d_ = dL + 16384 + (buf) * 32768 + (h) * 8192; \
    gload_lds16(d_, s_); gload_lds16(d_ + 4096, s_ + (size_t)64 * K); } while (0)

// read A frags mi in [miBase, miBase+4), both K-slices
#define RD_A(buf, miBase, d0, d1) do { _Pragma("unroll") \
    for (int m = 0; m < 4; ++m) { \
        const u16* p_ = lds + (buf) * 32768 + wm * 8192 + ((miBase) + m) * 1024 + aRow; \
        d0[m] = *(const bf16x8*)(p_ + cOf0); \
        d1[m] = *(const bf16x8*)(p_ + cOf1); } } while (0)
// read B frags ni in [niBase, niBase+2), both K-slices.
// B-row = ni*64 + wn*16 + lr -> half = ni>>1, row_in_half = (ni&1)*64+wn*16+lr
#define RD_B(buf, niBase, d0, d1) do { _Pragma("unroll") \
    for (int n = 0; n < 2; ++n) { \
        const int ni_ = (niBase) + n; \
        const u16* p_ = lds + (buf) * 32768 + 16384 + (ni_ >> 1) * 8192 + \
                        ((ni_ & 1) * 64 + wn * 16) * 64 + aRow; \
        d0[n] = *(const bf16x8*)(p_ + cOf0); \
        d1[n] = *(const bf16x8*)(p_ + cOf1); } } while (0)

#define MM(miBase, niBase, A0, A1, B0, B1) do { \
    __builtin_amdgcn_s_setprio(1); \
    _Pragma("unroll") for (int m = 0; m < 4; ++m) \
    _Pragma("unroll") for (int n = 0; n < 2; ++n) { \
        acc[(miBase) + m][(niBase) + n] = __builtin_amdgcn_mfma_f32_16x16x32_bf16( \
            A0[m], B0[n], acc[(miBase) + m][(niBase) + n], 0, 0, 0); \
        acc[(miBase) + m][(niBase) + n] = __builtin_amdgcn_mfma_f32_16x16x32_bf16( \
            A1[m], B1[n], acc[(miBase) + m][(niBase) + n], 0, 0, 0); } \
    __builtin_amdgcn_s_setprio(0); } while (0)

template <typename OutT, bool ROPE>
__global__ __launch_bounds__(512, 2) void gemm256(const u16* __restrict__ A,
                                                  const u16* __restrict__ Bt,
                                                  OutT* __restrict__ C,
                                                  const float2* __restrict__ tab,
                                                  int M, int N, int K) {
    __shared__ u16 lds[65536];   // 2 bufs x (A 256x64 + B 256x64) bf16 = 128 KiB
    const int tid  = threadIdx.x;
    const int lane = tid & 63;
    const int wid  = tid >> 6;
    const int wm = wid >> 2;           // 0..1 -> 128 rows each
    const int wn = wid & 3;            // 0..3 -> 16-col granules (col=ni*64+wn*16+lr)
    const int lr  = lane & 15;
    const int kq  = lane >> 4;         // 0..3
    const int lr7 = lr & 7;
    const int aRow = lr * 64;                       // row offset within half (elems)
    const int cOf0 = ((kq) ^ lr7) << 3;             // K-slice 0 chunk (swizzled)
    const int cOf1 = ((4 + kq) ^ lr7) << 3;         // K-slice 1 chunk

    // ---- 2D-chunked XCD tile mapping (bijective; FETCH 551->202MB) ----
    const int nwg = gridDim.x;
    const int bid = blockIdx.x;
    const int numM = M >> 8;
    int tileR, tileC;
    if (numM == 32 && nwg == 512) {
        const int x = bid & 7, i = bid >> 3;
        tileR = ((x >> 1) << 3) + (i & 7);
        tileC = ((x & 1) << 3) + (i >> 3);
    } else {
        const int cpx = nwg >> 3;
        const int swz = (bid & 7) * cpx + (bid >> 3);
        tileR = swz % numM;
        tileC = swz / numM;
    }
    const size_t rowBase = (size_t)tileR << 8;
    const size_t colBase = (size_t)tileC << 8;

    // staging addresses: half-tile = 1024 chunks of 16B; thread owns chunks
    // tid (row r0=tid>>3) and tid+512 (row r0+64); src col pre-swizzled.
    const int r0 = tid >> 3;
    const int cS = (((tid & 7) ^ (r0 & 7)) << 3);
    const u16* sA = A  + (rowBase + r0) * (size_t)K + cS;
    const u16* sB = Bt + (colBase + r0) * (size_t)K + cS;
    u16* dL = &lds[0] + tid * 8;       // linear chunk dest (+4096 elems for chunk tid+512)

    f32x4 acc[8][4];
#pragma unroll
    for (int i = 0; i < 8; ++i)
#pragma unroll
        for (int j = 0; j < 4; ++j)
            acc[i][j] = (f32x4){0.f, 0.f, 0.f, 0.f};

    bf16x8 a0K0[4], a0K1[4], a4K0[4], a4K1[4];
    bf16x8 b01eK0[2], b01eK1[2], b01oK0[2], b01oK1[2], b23K0[2], b23K1[2];

    // prologue: buf0 <- tile0, buf1.B <- tile1; drain buf0 (leave buf1.B in
    // flight), publish, then pre-read P0's operands (a03+b01_e of tile0).
    STG_A(0, 0, 0); STG_A(0, 1, 0); STG_B(0, 0, 0); STG_B(0, 1, 0);
    STG_B(1, 0, 64); STG_B(1, 1, 64);
    VMC(4);
    BARSPUB();
    RD_A(0, 0, a0K0, a0K1);
    RD_B(0, 0, b01eK0, b01eK1);

    const int nIter = K >> 7;          // K/128, K % 128 == 0
    for (int it = 0; it < nIter; ++it) {
        const int k1  = ((it << 1) + 1) << 6;                    // tile 2i+1 (always valid)
        const int kt2 = ((it << 1) + 2) << 6;
        const int kt3 = ((it << 1) + 3) << 6;
        const int k2c = (kt2 <= K - 64) ? kt2 : 0;               // clamp OOB tail stages
        const int k3c = (kt3 <= K - 64) ? kt3 : 0;               // (data never consumed)

        // P0: read b23(buf0) PRE-bar (published @P7-prev) ; MFMA Q00
        STG_A(1, 0, k1);
        RD_B(0, 2, b23K0, b23K1);
        BARS();
        MM(0, 0, a0K0, a0K1, b01eK0, b01eK1);
        // P1: read a47(buf0) PRE-bar (published @P7-prev) ; MFMA Q02
        STG_A(1, 1, k1);
        RD_A(0, 4, a4K0, a4K1);
        BARS();
        MM(0, 2, a0K0, a0K1, b23K0, b23K1);
        // P2: MFMA Q42 ; no reads
        STG_B(0, 0, k2c);
        BARS();
        MM(4, 2, a4K0, a4K1, b23K0, b23K1);
        // P3: drain buf1, publish ; reads MUST stay post-bar ; MFMA Q40
        STG_B(0, 1, k2c);
        VMC(4);
        BARSPUB();
        RD_A(1, 0, a0K0, a0K1);
        RD_B(1, 0, b01oK0, b01oK1);
        MM(4, 0, a4K0, a4K1, b01eK0, b01eK1);
        // P4: read b23(buf1) PRE-bar (published @P3) ; MFMA Q00'
        STG_A(0, 0, k2c);
        RD_B(1, 2, b23K0, b23K1);
        BARS();
        MM(0, 0, a0K0, a0K1, b01oK0, b01oK1);
        // P5: read a47(buf1) PRE-bar (published @P3) ; MFMA Q02'
        STG_A(0, 1, k2c);
        RD_A(1, 4, a4K0, a4K1);
        BARS();
        MM(0, 2, a0K0, a0K1, b23K0, b23K1);
        // P6: MFMA Q42' ; no reads
        STG_B(1, 0, k3c);
        BARS();
        MM(4, 2, a4K0, a4K1, b23K0, b23K1);
        // P7: drain buf0, publish ; reads post-bar ; MFMA Q40'
        STG_B(1, 1, k3c);
        VMC(4);
        BARSPUB();
        RD_A(0, 0, a0K0, a0K1);
        RD_B(0, 0, b01eK0, b01eK1);
        MM(4, 0, a4K0, a4K1, b01oK0, b01oK1);
    }

    asm volatile("s_waitcnt vmcnt(0)" ::: "memory");   // drain leftover stages

    // epilogue: C/D frag layout col = lane&15, row = 4*(lane>>4) + r.
    // Global col = colBase + ni*64 + wn*16 + lr.
    if constexpr (ROPE) {
        const int dIdx = wn * 16 + lr;                   // uniform per lane
#pragma unroll
        for (int mi = 0; mi < 8; ++mi)
#pragma unroll
            for (int r = 0; r < 4; ++r) {
                size_t row = rowBase + wm * 128 + mi * 16 + (kq << 2) + r;
                float2 cs = tab[row * 64 + dIdx];        // (cos, sin) — no libm here
#pragma unroll
                for (int hp = 0; hp < 2; ++hp) {
                    float x1 = acc[mi][hp * 2 + 0][r];
                    float x2 = acc[mi][hp * 2 + 1][r];
                    size_t c1 = colBase + hp * 128 + wn * 16 + lr;
                    C[row * (size_t)N + c1]      = f2bf(x1 * cs.x - x2 * cs.y);
                    C[row * (size_t)N + c1 + 64] = f2bf(x2 * cs.x + x1 * cs.y);
                }
            }
    } else {
#pragma unroll
        for (int mi = 0; mi < 8; ++mi)
#pragma unroll
            for (int ni = 0; ni < 4; ++ni)
#pragma unroll
                for (int r = 0; r < 4; ++r) {
                    size_t row = rowBase + wm * 128 + mi * 16 + (kq << 2) + r;
                    size_t col = colBase + ni * 64 + wn * 16 + lr;
                    store_out(&C[row * (size_t)N + col], acc[mi][ni][r]);
                }
    }
}

extern "C" void kernel_launch(void* const* d_in, const int* in_sizes, int n_in,
                              void* d_out, int out_size, void* d_ws, size_t ws_size,
                              hipStream_t stream) {
    const float* hidden    = (const float*)d_in[0];   // [T][E] fp32
    const int*   positions = (const int*)d_in[1];     // [T] int32
    const float* w_qkv     = (const float*)d_in[2];   // [E][6144] fp32
    const float* w_o       = (const float*)d_in[3];   // [QSZ][E] fp32
    float* out = (float*)d_out;                       // [T][E] fp32

    // workspace layout (bf16): H 64MiB | WqT 32MiB | WoT 32MiB | Q 64MiB = 192MiB.
    // Preferred: tab gets its own 4MiB at 192MiB (ws >= 196MiB) -> Wo-transpose
    // fuses into the prepass. Fallback: tab aliases WoT; Wo-transpose runs
    // between the GEMMs.
    u16* Hb  = (u16*)d_ws;
    u16* WqT = Hb  + (size_t)T_DIM * E_DIM;
    u16* WoT = WqT + (size_t)QSZ * E_DIM;
    u16* Qb  = WoT + (size_t)E_DIM * QSZ;
    const bool fuseWo = ws_size >= ((size_t)196 << 20);
    float2* tab = fuseWo ? (float2*)(Qb + (size_t)T_DIM * QSZ)   // own region @192MiB
                         : (float2*)WoT;                          // alias (fallback)

    if (fuseWo) {
        // 1) ONE fused pre-pass: H convert + Wq-T + Wo-T + RoPE table
        prepass<true><<<CONV_BLOCKS + TWQ_BLOCKS + TWO_BLOCKS + TAB_BLOCKS, 256, 0, stream>>>(
            hidden, Hb, w_qkv, WqT, w_o, WoT, positions, tab);

        // 2) Q = rope(H @ Wq)
        gemm256<u16, true><<<dim3((T_DIM / 256) * (QSZ / 256)), 512, 0, stream>>>(
            Hb, WqT, Qb, tab, T_DIM, QSZ, E_DIM);

        // 3) out = Q @ Wo  (no mid-stream transpose — zero bubble)
        gemm256<float, false><<<dim3((T_DIM / 256) * (E_DIM / 256)), 512, 0, stream>>>(
            Qb, WoT, out, nullptr, T_DIM, E_DIM, QSZ);
    } else {
        // Fallback (r11 measured path)
        prepass<false><<<CONV_BLOCKS + TWQ_BLOCKS + TAB_BLOCKS, 256, 0, stream>>>(
            hidden, Hb, w_qkv, WqT, w_o, WoT, positions, tab);
        gemm256<u16, true><<<dim3((T_DIM / 256) * (QSZ / 256)), 512, 0, stream>>>(
            Hb, WqT, Qb, tab, T_DIM, QSZ, E_DIM);
        dim3 tb(32, 8);
        transpose_conv<<<dim3(E_DIM / 32, QSZ / 32), tb, 0, stream>>>(w_o, WoT, QSZ, E_DIM, E_DIM, 0);
        gemm256<float, false><<<dim3((T_DIM / 256) * (E_DIM / 256)), 512, 0, stream>>>(
            Qb, WoT, out, nullptr, T_DIM, E_DIM, QSZ);
    }
}